// Round 15
// baseline (1180.542 us; speedup 1.0000x reference)
//
#include <hip/hip_runtime.h>
#include <hip/hip_bf16.h>
#include <stdint.h>

#define B_SZ 4096
#define D_SZ 2048

typedef __attribute__((ext_vector_type(4))) float f32x4;
typedef __attribute__((ext_vector_type(8))) __bf16 bf16x8;
typedef __attribute__((ext_vector_type(4))) unsigned short u16x4;
typedef unsigned short u16;

static constexpr long BD = (long)B_SZ * D_SZ;   // 8388608
static constexpr long DD = (long)D_SZ * D_SZ;   // 4194304

__device__ __forceinline__ u16 f2bf(float f) {
  union { float f; unsigned int u; } c; c.f = f;
  unsigned int u = c.u;
  u = (u + 0x7fffu + ((u >> 16) & 1u)) >> 16;
  return (u16)u;
}

// ---------------------------------------------------------------- convert (all bf16)
__global__ __launch_bounds__(256) void k_convert(
    const float* __restrict__ x,  const float* __restrict__ wr,
    const float* __restrict__ wk, const float* __restrict__ wv,
    const float* __restrict__ wo,
    u16* __restrict__ Xb, u16* __restrict__ W3b, u16* __restrict__ Wob) {
  long i = ((long)blockIdx.x * 256 + threadIdx.x) * 4;
  const float* src; u16* dst; long so, dofs;
  if (i < BD)               { src = x;  so = i;            dst = Xb;  dofs = so; }
  else if (i < BD + DD)     { src = wr; so = i - BD;       dst = W3b; dofs = i - BD; }
  else if (i < BD + 2*DD)   { src = wk; so = i - BD - DD;  dst = W3b; dofs = i - BD; }
  else if (i < BD + 3*DD)   { src = wv; so = i - BD - 2*DD; dst = W3b; dofs = i - BD; }
  else                      { src = wo; so = i - BD - 3*DD; dst = Wob; dofs = so; }
  f32x4 v = *reinterpret_cast<const f32x4*>(src + so);
  u16x4 o;
  o[0] = f2bf(v[0]); o[1] = f2bf(v[1]); o[2] = f2bf(v[2]); o[3] = f2bf(v[3]);
  *reinterpret_cast<u16x4*>(dst + dofs) = o;
}

// ---------------------------------------------------------------- async global->LDS
__device__ __forceinline__ void gload16(const u16* g, const u16* l) {
  __builtin_amdgcn_global_load_lds(
      (const __attribute__((address_space(1))) unsigned int*)g,
      (__attribute__((address_space(3))) unsigned int*)l, 16, 0, 0);
}

#define FENCE asm volatile("" ::: "memory")
#define BAR do { FENCE; __builtin_amdgcn_s_barrier(); FENCE; } while (0)
#define VMC(n) asm volatile("s_waitcnt vmcnt(" #n ")" ::: "memory")

// ================================================================ fused bf16 rkv GEMM + WKV
// R9 economy, SINGLE-BUFFER 40 KiB variant: 4 blocks/CU (32 waves/CU, 8/SIMD).
// {domains x phase-length} experiment: doubles barrier domains vs R9 while keeping
// BK=64 phases (R10 showed short phases are the toxin, R5 showed domains pay).
// Within-block stage latency is serial-exposed; 4 anti-phased blocks cover it.
// VGPR must stay <=64: R9's non-hoisted COMPUTE (measured 52) + launch_bounds(512,8).
// Single-buffer safety: last MFMA's issue proves ds_reads drained (reg deps);
// BAR orders reads before STAGE's overwrite; VMC(0)+BAR proves staging before use.
__global__ __launch_bounds__(512, 8) void k_fused(
    const u16* __restrict__ A, const u16* __restrict__ W3,   // W3 = [Wr;Wk;Wv] rows
    const float* __restrict__ frac_n, const float* __restrict__ frac_d,
    const float* __restrict__ scale,
    const float* __restrict__ w_u, const float* __restrict__ w_w,
    float* __restrict__ o_nfn, float* __restrict__ o_nfd,
    float* __restrict__ o_ns,  u16* __restrict__ ab) {
  __shared__ __align__(16) u16 lds[20480];  // 40 KiB, single buffer
  const int tid = threadIdx.x;
  const int l   = tid & 63;
  const int wid = tid >> 6;    // 0..7
  const int wm  = wid >> 2;    // 0..1  (M half: 64 rows)
  const int wn  = wid & 3;     // 0..3  (N quarter: 16 cols)
  const int bm = blockIdx.y, bn = blockIdx.x;
  const int K  = D_SZ;
  const int NT = K >> 6;       // 32

  const int gcol = (((l & 7) ^ (l >> 3)) << 3);
  const u16* Abase = A + (long)(bm * 128 + wid * 16 + (l >> 3)) * K + gcol;
  const int i0 = wid * 3;

  #define STAGE(t) do {                                                        \
    const long _ko = (long)(t) * 64;                                           \
    gload16(Abase + _ko,                lds + wid * 1024);                     \
    gload16(Abase + 8 * (long)K + _ko,  lds + wid * 1024 + 512);               \
    _Pragma("unroll")                                                          \
    for (int _c = 0; _c < 3; ++_c) {                                           \
      const int _i = i0 + _c, _j = _i >> 3, _rc = _i & 7;                      \
      const u16* _g = W3 + (long)_j * DD                                       \
                    + (long)(bn * 64 + _rc * 8 + (l >> 3)) * K + gcol + _ko;   \
      gload16(_g, lds + 8192 + _j * 4096 + _rc * 512);                         \
    }                                                                          \
  } while (0)

  const int rby  = (l & 15) * 128;
  const int obx0 = ((l >> 4) * 16) ^ ((l & 7) << 4);
  const int lo0  = (rby + obx0) >> 1;      // u16 index
  const int lo1  = lo0 ^ 32;               // ks=1 (byte ^ 64)

  f32x4 acc[3][4] = {};

  auto COMPUTE = [&]() {
#pragma unroll
    for (int ks = 0; ks < 2; ++ks) {
      const int lo = ks ? lo1 : lo0;
      bf16x8 af[4], fb[3];
#pragma unroll
      for (int mi = 0; mi < 4; ++mi)
        af[mi] = *reinterpret_cast<const bf16x8*>(
            &lds[wm * 4096 + mi * 1024 + lo]);
#pragma unroll
      for (int j = 0; j < 3; ++j)
        fb[j] = *reinterpret_cast<const bf16x8*>(
            &lds[8192 + j * 4096 + wn * 1024 + lo]);
      __builtin_amdgcn_s_setprio(1);
#pragma unroll
      for (int j = 0; j < 3; ++j)
#pragma unroll
        for (int mi = 0; mi < 4; ++mi)
          acc[j][mi] = __builtin_amdgcn_mfma_f32_16x16x32_bf16(
              af[mi], fb[j], acc[j][mi], 0, 0, 0);
      __builtin_amdgcn_s_setprio(0);
    }
  };

  // ---- single-buffer loop: stage -> prove -> compute -> barrier -> restage
  STAGE(0);
  VMC(0); BAR;
  for (int t = 0; t < NT - 1; ++t) {
    COMPUTE();
    BAR;                 // all reads of buf done (MFMA reg-deps) before overwrite
    STAGE(t + 1);
    VMC(0); BAR;         // staging landed, collectively
  }
  COMPUTE();
  #undef STAGE

  // ---- fused WKV epilogue (fp32) -- R9-verbatim
  const long row0 = (long)bm * 128 + wm * 64 + (l >> 4) * 4;
  const long gc   = (long)bn * 64 + wn * 16 + (l & 15);
  const float wuv = w_u[gc];
  const float wwv = w_w[gc];
#pragma unroll
  for (int mi = 0; mi < 4; ++mi)
#pragma unroll
    for (int r = 0; r < 4; ++r) {
      const long gr  = row0 + mi * 16 + r;
      const long idx = gr * D_SZ + gc;
      const float rr = acc[0][mi][r];
      const float kk = acc[1][mi][r];
      const float vv = acc[2][mi][r];
      const float n  = frac_n[idx];
      const float dn = frac_d[idx];
      const float s  = scale[idx];

      const float rt  = 1.0f / (1.0f + __expf(-rr));
      const float ss  = fmaxf(s, wuv + kk);
      const float cm  = __expf(s - ss);
      const float am  = __expf(wuv + kk - ss);
      const float fnt = cm * n + am * vv;
      const float fdt = cm * dn + am;

      const float ns2 = fmaxf(s + wwv, kk);
      const float ncm = __expf(s + wwv - ns2);
      const float nam = __expf(kk - ns2);

      o_nfn[idx] = ncm * n + nam * vv;
      o_nfd[idx] = ncm * dn + nam;
      o_ns[idx]  = ns2;
      ab[idx]    = f2bf(rt * (fnt / fdt));
    }
}

// ================================================================ 128x128 bf16 GEMM (out-proj)
// R14 version (hoisted-fragment COMPUTE, measured == R9 baseline).
template <bool OUT_BF16>
__global__ __launch_bounds__(256, 4) void k_gemm128(
    const u16* __restrict__ A, const u16* __restrict__ Bm,
    void* __restrict__ C, int M, int N, int K) {
  __shared__ __align__(16) u16 lds[32768];  // 64 KiB
  const int tid = threadIdx.x;
  const int l   = tid & 63;
  const int w   = tid >> 6;
  const int wm  = w >> 1, wn = w & 1;
  const int bm = blockIdx.y, bn = blockIdx.x;
  const int NT = K >> 6;

  const int gcol  = (((l & 7) ^ (l >> 3)) << 3);
  const int grow  = w * 32 + (l >> 3);
  const u16* Abase = A  + (long)(bm * 128 + grow) * K + gcol;
  const u16* Bbase = Bm + (long)(bn * 128 + grow) * K + gcol;
  const int sdst = w * 2048;

  #define STAGE(t) do {                                              \
    const long _ko = (long)(t) * 64;                                 \
    u16* _da = &lds[((t) & 1) * 16384 + sdst];                       \
    u16* _db = _da + 8192;                                           \
    _Pragma("unroll")                                                \
    for (int _c = 0; _c < 4; ++_c) {                                 \
      gload16(Abase + (long)_c * 8 * K + _ko, _da + _c * 512);       \
      gload16(Bbase + (long)_c * 8 * K + _ko, _db + _c * 512);       \
    }                                                                \
  } while (0)

  const int rby  = (l & 15) * 128;
  const int obx0 = ((l >> 4) * 16) ^ ((l & 7) << 4);
  const int lo0  = (rby + obx0) >> 1;
  const int lo1  = lo0 ^ 32;

  f32x4 acc[4][4] = {};

  auto COMPUTE = [&](int p) {
    bf16x8 af[2][4], bf[2][4];
#pragma unroll
    for (int ks = 0; ks < 2; ++ks) {
      const int lo = ks ? lo1 : lo0;
#pragma unroll
      for (int mi = 0; mi < 4; ++mi)
        af[ks][mi] = *reinterpret_cast<const bf16x8*>(
            &lds[p * 16384 + (wm * 4 + mi) * 1024 + lo]);
#pragma unroll
      for (int ni = 0; ni < 4; ++ni)
        bf[ks][ni] = *reinterpret_cast<const bf16x8*>(
            &lds[p * 16384 + 8192 + (wn * 4 + ni) * 1024 + lo]);
    }
    __builtin_amdgcn_s_setprio(1);
#pragma unroll
    for (int ks = 0; ks < 2; ++ks)
#pragma unroll
      for (int mi = 0; mi < 4; ++mi)
#pragma unroll
        for (int ni = 0; ni < 4; ++ni)
          acc[mi][ni] = __builtin_amdgcn_mfma_f32_16x16x32_bf16(
              af[ks][mi], bf[ks][ni], acc[mi][ni], 0, 0, 0);
    __builtin_amdgcn_s_setprio(0);
  };

  STAGE(0);
  VMC(0); BAR;
  for (int t = 0; t < NT - 1; ++t) {
    STAGE(t + 1);
    COMPUTE(t & 1);
    VMC(0); BAR;
  }
  COMPUTE((NT - 1) & 1);
  #undef STAGE

  const int rb = (l >> 4) * 4, cb = l & 15;
  const long Crow0 = (long)bm * 128 + wm * 64 + rb;
  const long Ccol0 = (long)bn * 128 + wn * 64 + cb;
#pragma unroll
  for (int mi = 0; mi < 4; ++mi)
#pragma unroll
    for (int ni = 0; ni < 4; ++ni)
#pragma unroll
      for (int r = 0; r < 4; ++r) {
        const long gr = Crow0 + mi * 16 + r;
        const long gc = Ccol0 + ni * 16;
        if constexpr (OUT_BF16)
          ((u16*)C)[gr * N + gc] = f2bf(acc[mi][ni][r]);
        else
          ((float*)C)[gr * N + gc] = acc[mi][ni][r];
      }
}

// ---------------------------------------------------------------- launch
extern "C" void kernel_launch(void* const* d_in, const int* in_sizes, int n_in,
                              void* d_out, int out_size, void* d_ws, size_t ws_size,
                              hipStream_t stream) {
  const float* x      = (const float*)d_in[0];
  const float* frac_n = (const float*)d_in[1];
  const float* frac_d = (const float*)d_in[2];
  const float* scale  = (const float*)d_in[3];
  const float* wr     = (const float*)d_in[4];
  const float* wk     = (const float*)d_in[5];
  const float* wv     = (const float*)d_in[6];
  const float* wo     = (const float*)d_in[7];
  const float* wu     = (const float*)d_in[8];
  const float* ww     = (const float*)d_in[9];
  float* out = (float*)d_out;

  u16* Xb   = (u16*)d_ws;        // BD
  u16* W3b  = Xb + BD;           // 3*DD  (w_r | w_k | w_v rows)
  u16* Wob  = W3b + 3 * DD;      // DD
  u16* ab   = Wob + DD;          // BD

  // 1) fp32 -> bf16 conversions
  {
    const long total = BD + 4 * DD;             // 25165824
    const int blocks = (int)(total / 4 / 256);  // 24576 exact
    k_convert<<<blocks, 256, 0, stream>>>(x, wr, wk, wv, wo, Xb, W3b, Wob);
  }
  // 2) fused rkv GEMM + WKV elementwise (single-buffer, 4 blocks/CU, zero tail)
  //    grid 32x32 = 1024 blocks = exactly 4 blocks/CU in ONE round
  k_fused<<<dim3(D_SZ / 64, B_SZ / 128), 512, 0, stream>>>(
      Xb, W3b, frac_n, frac_d, scale, wu, ww,
      out + BD, out + 2 * BD, out + 3 * BD, ab);
  // 3) output = a @ Wo^T -> d_out[0:BD] fp32
  k_gemm128<false><<<dim3(D_SZ / 128, B_SZ / 128), 256, 0, stream>>>(
      ab, Wob, out, B_SZ, D_SZ, D_SZ);
}

// Round 16
// 297.676 us; speedup vs baseline: 3.9659x; 3.9659x over previous
//
#include <hip/hip_runtime.h>
#include <hip/hip_bf16.h>
#include <stdint.h>

#define B_SZ 4096
#define D_SZ 2048

typedef __attribute__((ext_vector_type(4))) float f32x4;
typedef __attribute__((ext_vector_type(8))) __bf16 bf16x8;
typedef __attribute__((ext_vector_type(4))) unsigned short u16x4;
typedef unsigned short u16;

static constexpr long BD = (long)B_SZ * D_SZ;   // 8388608
static constexpr long DD = (long)D_SZ * D_SZ;   // 4194304

__device__ __forceinline__ u16 f2bf(float f) {
  union { float f; unsigned int u; } c; c.f = f;
  unsigned int u = c.u;
  u = (u + 0x7fffu + ((u >> 16) & 1u)) >> 16;
  return (u16)u;
}

// ---------------------------------------------------------------- convert (all bf16)
__global__ __launch_bounds__(256) void k_convert(
    const float* __restrict__ x,  const float* __restrict__ wr,
    const float* __restrict__ wk, const float* __restrict__ wv,
    const float* __restrict__ wo,
    u16* __restrict__ Xb, u16* __restrict__ W3b, u16* __restrict__ Wob) {
  long i = ((long)blockIdx.x * 256 + threadIdx.x) * 4;
  const float* src; u16* dst; long so, dofs;
  if (i < BD)               { src = x;  so = i;            dst = Xb;  dofs = so; }
  else if (i < BD + DD)     { src = wr; so = i - BD;       dst = W3b; dofs = i - BD; }
  else if (i < BD + 2*DD)   { src = wk; so = i - BD - DD;  dst = W3b; dofs = i - BD; }
  else if (i < BD + 3*DD)   { src = wv; so = i - BD - 2*DD; dst = W3b; dofs = i - BD; }
  else                      { src = wo; so = i - BD - 3*DD; dst = Wob; dofs = so; }
  f32x4 v = *reinterpret_cast<const f32x4*>(src + so);
  u16x4 o;
  o[0] = f2bf(v[0]); o[1] = f2bf(v[1]); o[2] = f2bf(v[2]); o[3] = f2bf(v[3]);
  *reinterpret_cast<u16x4*>(dst + dofs) = o;
}

// ---------------------------------------------------------------- async global->LDS
__device__ __forceinline__ void gload16(const u16* g, const u16* l) {
  __builtin_amdgcn_global_load_lds(
      (const __attribute__((address_space(1))) unsigned int*)g,
      (__attribute__((address_space(3))) unsigned int*)l, 16, 0, 0);
}

#define FENCE asm volatile("" ::: "memory")
#define BAR do { FENCE; __builtin_amdgcn_s_barrier(); FENCE; } while (0)
#define VMC(n) asm volatile("s_waitcnt vmcnt(" #n ")" ::: "memory")

// ================================================================ fused bf16 rkv GEMM + WKV
// Single-buffer 40 KiB, THREE blocks/CU (24 waves/CU, 6/SIMD).
// R15's structure was correct (absmax OK); its (512,8) bound forced a 64-reg
// unified budget -> 48-AGPR acc spilled (3 GB scratch). (512,6) gives an 85-reg
// budget; R9's COMPUTE measured 52 -> fits, no spill. 3 independent barrier
// domains push the LDS port from 63% busy (R9, 2 domains) toward saturation.
__global__ __launch_bounds__(512, 6) void k_fused(
    const u16* __restrict__ A, const u16* __restrict__ W3,   // W3 = [Wr;Wk;Wv] rows
    const float* __restrict__ frac_n, const float* __restrict__ frac_d,
    const float* __restrict__ scale,
    const float* __restrict__ w_u, const float* __restrict__ w_w,
    float* __restrict__ o_nfn, float* __restrict__ o_nfd,
    float* __restrict__ o_ns,  u16* __restrict__ ab) {
  __shared__ __align__(16) u16 lds[20480];  // 40 KiB, single buffer
  const int tid = threadIdx.x;
  const int l   = tid & 63;
  const int wid = tid >> 6;    // 0..7
  const int wm  = wid >> 2;    // 0..1  (M half: 64 rows)
  const int wn  = wid & 3;     // 0..3  (N quarter: 16 cols)
  const int bm = blockIdx.y, bn = blockIdx.x;
  const int K  = D_SZ;
  const int NT = K >> 6;       // 32

  const int gcol = (((l & 7) ^ (l >> 3)) << 3);
  const u16* Abase = A + (long)(bm * 128 + wid * 16 + (l >> 3)) * K + gcol;
  const int i0 = wid * 3;

  #define STAGE(t) do {                                                        \
    const long _ko = (long)(t) * 64;                                           \
    gload16(Abase + _ko,                lds + wid * 1024);                     \
    gload16(Abase + 8 * (long)K + _ko,  lds + wid * 1024 + 512);               \
    _Pragma("unroll")                                                          \
    for (int _c = 0; _c < 3; ++_c) {                                           \
      const int _i = i0 + _c, _j = _i >> 3, _rc = _i & 7;                      \
      const u16* _g = W3 + (long)_j * DD                                       \
                    + (long)(bn * 64 + _rc * 8 + (l >> 3)) * K + gcol + _ko;   \
      gload16(_g, lds + 8192 + _j * 4096 + _rc * 512);                         \
    }                                                                          \
  } while (0)

  const int rby  = (l & 15) * 128;
  const int obx0 = ((l >> 4) * 16) ^ ((l & 7) << 4);
  const int lo0  = (rby + obx0) >> 1;      // u16 index
  const int lo1  = lo0 ^ 32;               // ks=1 (byte ^ 64)

  f32x4 acc[3][4] = {};

  auto COMPUTE = [&]() {
#pragma unroll
    for (int ks = 0; ks < 2; ++ks) {
      const int lo = ks ? lo1 : lo0;
      bf16x8 af[4], fb[3];
#pragma unroll
      for (int mi = 0; mi < 4; ++mi)
        af[mi] = *reinterpret_cast<const bf16x8*>(
            &lds[wm * 4096 + mi * 1024 + lo]);
#pragma unroll
      for (int j = 0; j < 3; ++j)
        fb[j] = *reinterpret_cast<const bf16x8*>(
            &lds[8192 + j * 4096 + wn * 1024 + lo]);
      __builtin_amdgcn_s_setprio(1);
#pragma unroll
      for (int j = 0; j < 3; ++j)
#pragma unroll
        for (int mi = 0; mi < 4; ++mi)
          acc[j][mi] = __builtin_amdgcn_mfma_f32_16x16x32_bf16(
              af[mi], fb[j], acc[j][mi], 0, 0, 0);
      __builtin_amdgcn_s_setprio(0);
    }
  };

  // ---- single-buffer loop: stage -> prove -> compute -> barrier -> restage
  STAGE(0);
  VMC(0); BAR;
  for (int t = 0; t < NT - 1; ++t) {
    COMPUTE();
    BAR;                 // all reads of buf done (MFMA reg-deps) before overwrite
    STAGE(t + 1);
    VMC(0); BAR;         // staging landed, collectively
  }
  COMPUTE();
  #undef STAGE

  // ---- fused WKV epilogue (fp32) -- R9-verbatim
  const long row0 = (long)bm * 128 + wm * 64 + (l >> 4) * 4;
  const long gc   = (long)bn * 64 + wn * 16 + (l & 15);
  const float wuv = w_u[gc];
  const float wwv = w_w[gc];
#pragma unroll
  for (int mi = 0; mi < 4; ++mi)
#pragma unroll
    for (int r = 0; r < 4; ++r) {
      const long gr  = row0 + mi * 16 + r;
      const long idx = gr * D_SZ + gc;
      const float rr = acc[0][mi][r];
      const float kk = acc[1][mi][r];
      const float vv = acc[2][mi][r];
      const float n  = frac_n[idx];
      const float dn = frac_d[idx];
      const float s  = scale[idx];

      const float rt  = 1.0f / (1.0f + __expf(-rr));
      const float ss  = fmaxf(s, wuv + kk);
      const float cm  = __expf(s - ss);
      const float am  = __expf(wuv + kk - ss);
      const float fnt = cm * n + am * vv;
      const float fdt = cm * dn + am;

      const float ns2 = fmaxf(s + wwv, kk);
      const float ncm = __expf(s + wwv - ns2);
      const float nam = __expf(kk - ns2);

      o_nfn[idx] = ncm * n + nam * vv;
      o_nfd[idx] = ncm * dn + nam;
      o_ns[idx]  = ns2;
      ab[idx]    = f2bf(rt * (fnt / fdt));
    }
}

// ================================================================ 128x128 bf16 GEMM (out-proj)
// R14 version (hoisted-fragment COMPUTE, measured == R9 baseline).
template <bool OUT_BF16>
__global__ __launch_bounds__(256, 4) void k_gemm128(
    const u16* __restrict__ A, const u16* __restrict__ Bm,
    void* __restrict__ C, int M, int N, int K) {
  __shared__ __align__(16) u16 lds[32768];  // 64 KiB
  const int tid = threadIdx.x;
  const int l   = tid & 63;
  const int w   = tid >> 6;
  const int wm  = w >> 1, wn = w & 1;
  const int bm = blockIdx.y, bn = blockIdx.x;
  const int NT = K >> 6;

  const int gcol  = (((l & 7) ^ (l >> 3)) << 3);
  const int grow  = w * 32 + (l >> 3);
  const u16* Abase = A  + (long)(bm * 128 + grow) * K + gcol;
  const u16* Bbase = Bm + (long)(bn * 128 + grow) * K + gcol;
  const int sdst = w * 2048;

  #define STAGE(t) do {                                              \
    const long _ko = (long)(t) * 64;                                 \
    u16* _da = &lds[((t) & 1) * 16384 + sdst];                       \
    u16* _db = _da + 8192;                                           \
    _Pragma("unroll")                                                \
    for (int _c = 0; _c < 4; ++_c) {                                 \
      gload16(Abase + (long)_c * 8 * K + _ko, _da + _c * 512);       \
      gload16(Bbase + (long)_c * 8 * K + _ko, _db + _c * 512);       \
    }                                                                \
  } while (0)

  const int rby  = (l & 15) * 128;
  const int obx0 = ((l >> 4) * 16) ^ ((l & 7) << 4);
  const int lo0  = (rby + obx0) >> 1;
  const int lo1  = lo0 ^ 32;

  f32x4 acc[4][4] = {};

  auto COMPUTE = [&](int p) {
    bf16x8 af[2][4], bf[2][4];
#pragma unroll
    for (int ks = 0; ks < 2; ++ks) {
      const int lo = ks ? lo1 : lo0;
#pragma unroll
      for (int mi = 0; mi < 4; ++mi)
        af[ks][mi] = *reinterpret_cast<const bf16x8*>(
            &lds[p * 16384 + (wm * 4 + mi) * 1024 + lo]);
#pragma unroll
      for (int ni = 0; ni < 4; ++ni)
        bf[ks][ni] = *reinterpret_cast<const bf16x8*>(
            &lds[p * 16384 + 8192 + (wn * 4 + ni) * 1024 + lo]);
    }
    __builtin_amdgcn_s_setprio(1);
#pragma unroll
    for (int ks = 0; ks < 2; ++ks)
#pragma unroll
      for (int mi = 0; mi < 4; ++mi)
#pragma unroll
        for (int ni = 0; ni < 4; ++ni)
          acc[mi][ni] = __builtin_amdgcn_mfma_f32_16x16x32_bf16(
              af[ks][mi], bf[ks][ni], acc[mi][ni], 0, 0, 0);
    __builtin_amdgcn_s_setprio(0);
  };

  STAGE(0);
  VMC(0); BAR;
  for (int t = 0; t < NT - 1; ++t) {
    STAGE(t + 1);
    COMPUTE(t & 1);
    VMC(0); BAR;
  }
  COMPUTE((NT - 1) & 1);
  #undef STAGE

  const int rb = (l >> 4) * 4, cb = l & 15;
  const long Crow0 = (long)bm * 128 + wm * 64 + rb;
  const long Ccol0 = (long)bn * 128 + wn * 64 + cb;
#pragma unroll
  for (int mi = 0; mi < 4; ++mi)
#pragma unroll
    for (int ni = 0; ni < 4; ++ni)
#pragma unroll
      for (int r = 0; r < 4; ++r) {
        const long gr = Crow0 + mi * 16 + r;
        const long gc = Ccol0 + ni * 16;
        if constexpr (OUT_BF16)
          ((u16*)C)[gr * N + gc] = f2bf(acc[mi][ni][r]);
        else
          ((float*)C)[gr * N + gc] = acc[mi][ni][r];
      }
}

// ---------------------------------------------------------------- launch
extern "C" void kernel_launch(void* const* d_in, const int* in_sizes, int n_in,
                              void* d_out, int out_size, void* d_ws, size_t ws_size,
                              hipStream_t stream) {
  const float* x      = (const float*)d_in[0];
  const float* frac_n = (const float*)d_in[1];
  const float* frac_d = (const float*)d_in[2];
  const float* scale  = (const float*)d_in[3];
  const float* wr     = (const float*)d_in[4];
  const float* wk     = (const float*)d_in[5];
  const float* wv     = (const float*)d_in[6];
  const float* wo     = (const float*)d_in[7];
  const float* wu     = (const float*)d_in[8];
  const float* ww     = (const float*)d_in[9];
  float* out = (float*)d_out;

  u16* Xb   = (u16*)d_ws;        // BD
  u16* W3b  = Xb + BD;           // 3*DD  (w_r | w_k | w_v rows)
  u16* Wob  = W3b + 3 * DD;      // DD
  u16* ab   = Wob + DD;          // BD

  // 1) fp32 -> bf16 conversions
  {
    const long total = BD + 4 * DD;             // 25165824
    const int blocks = (int)(total / 4 / 256);  // 24576 exact
    k_convert<<<blocks, 256, 0, stream>>>(x, wr, wk, wv, wo, Xb, W3b, Wob);
  }
  // 2) fused rkv GEMM + WKV elementwise (single-buffer, 3 blocks/CU)
  k_fused<<<dim3(D_SZ / 64, B_SZ / 128), 512, 0, stream>>>(
      Xb, W3b, frac_n, frac_d, scale, wu, ww,
      out + BD, out + 2 * BD, out + 3 * BD, ab);
  // 3) output = a @ Wo^T -> d_out[0:BD] fp32
  k_gemm128<false><<<dim3(D_SZ / 128, B_SZ / 128), 256, 0, stream>>>(
      ab, Wob, out, B_SZ, D_SZ, D_SZ);
}

// Round 17
// 198.093 us; speedup vs baseline: 5.9595x; 1.5027x over previous
//
#include <hip/hip_runtime.h>
#include <hip/hip_bf16.h>
#include <stdint.h>

#define B_SZ 4096
#define D_SZ 2048

typedef __attribute__((ext_vector_type(4))) float f32x4;
typedef __attribute__((ext_vector_type(8))) __bf16 bf16x8;
typedef __attribute__((ext_vector_type(4))) unsigned short u16x4;
typedef unsigned short u16;

static constexpr long BD = (long)B_SZ * D_SZ;   // 8388608
static constexpr long DD = (long)D_SZ * D_SZ;   // 4194304

__device__ __forceinline__ u16 f2bf(float f) {
  union { float f; unsigned int u; } c; c.f = f;
  unsigned int u = c.u;
  u = (u + 0x7fffu + ((u >> 16) & 1u)) >> 16;
  return (u16)u;
}

// ---------------------------------------------------------------- convert (all bf16)
__global__ __launch_bounds__(256) void k_convert(
    const float* __restrict__ x,  const float* __restrict__ wr,
    const float* __restrict__ wk, const float* __restrict__ wv,
    const float* __restrict__ wo,
    u16* __restrict__ Xb, u16* __restrict__ W3b, u16* __restrict__ Wob) {
  long i = ((long)blockIdx.x * 256 + threadIdx.x) * 4;
  const float* src; u16* dst; long so, dofs;
  if (i < BD)               { src = x;  so = i;            dst = Xb;  dofs = so; }
  else if (i < BD + DD)     { src = wr; so = i - BD;       dst = W3b; dofs = i - BD; }
  else if (i < BD + 2*DD)   { src = wk; so = i - BD - DD;  dst = W3b; dofs = i - BD; }
  else if (i < BD + 3*DD)   { src = wv; so = i - BD - 2*DD; dst = W3b; dofs = i - BD; }
  else                      { src = wo; so = i - BD - 3*DD; dst = Wob; dofs = so; }
  f32x4 v = *reinterpret_cast<const f32x4*>(src + so);
  u16x4 o;
  o[0] = f2bf(v[0]); o[1] = f2bf(v[1]); o[2] = f2bf(v[2]); o[3] = f2bf(v[3]);
  *reinterpret_cast<u16x4*>(dst + dofs) = o;
}

// ---------------------------------------------------------------- async global->LDS
__device__ __forceinline__ void gload16(const u16* g, const u16* l) {
  __builtin_amdgcn_global_load_lds(
      (const __attribute__((address_space(1))) unsigned int*)g,
      (__attribute__((address_space(3))) unsigned int*)l, 16, 0, 0);
}

#define FENCE asm volatile("" ::: "memory")
#define BAR do { FENCE; __builtin_amdgcn_s_barrier(); FENCE; } while (0)
#define VMC(n) asm volatile("s_waitcnt vmcnt(" #n ")" ::: "memory")

// ================================================================ fused bf16 rkv GEMM + WKV
// EXACT R9 version -- best measured (total 199.9 us, k_fused 140.3 us).
// Block tile 128M x 64D x 3 (r,k,v); BK=64; 512 thr = 8 waves (2M x 4N);
// wave tile 64x16 per matrix; acc[3][4] = 48 regs (VGPR_Count 52);
// LDS 80 KiB double-buffered -> 2 blocks/CU, grid 1024 = 2 exact rounds.
// Wave decomposition is the LDS-traffic-optimal integer split for 3-matrix B
// (A-amp 4 x 16KB + B-amp 2 x 24KB = 112 KB/K-tile; all alternatives worse).
__global__ __launch_bounds__(512, 4) void k_fused(
    const u16* __restrict__ A, const u16* __restrict__ W3,   // W3 = [Wr;Wk;Wv] rows
    const float* __restrict__ frac_n, const float* __restrict__ frac_d,
    const float* __restrict__ scale,
    const float* __restrict__ w_u, const float* __restrict__ w_w,
    float* __restrict__ o_nfn, float* __restrict__ o_nfd,
    float* __restrict__ o_ns,  u16* __restrict__ ab) {
  __shared__ __align__(16) u16 lds[40960];  // 80 KiB: buf p at p*20480 (u16)
  const int tid = threadIdx.x;
  const int l   = tid & 63;
  const int wid = tid >> 6;    // 0..7
  const int wm  = wid >> 2;    // 0..1  (M half: 64 rows)
  const int wn  = wid & 3;     // 0..3  (N quarter: 16 cols)
  const int bm = blockIdx.y, bn = blockIdx.x;
  const int K  = D_SZ;
  const int NT = K >> 6;       // 32

  const int gcol = (((l & 7) ^ (l >> 3)) << 3);
  const u16* Abase = A + (long)(bm * 128 + wid * 16 + (l >> 3)) * K + gcol;
  const int i0 = wid * 3;

  #define STAGE(t) do {                                                        \
    const long _ko = (long)(t) * 64;                                           \
    u16* _b = &lds[((t) & 1) * 20480];                                         \
    gload16(Abase + _ko,                _b + wid * 1024);                      \
    gload16(Abase + 8 * (long)K + _ko,  _b + wid * 1024 + 512);                \
    _Pragma("unroll")                                                          \
    for (int _c = 0; _c < 3; ++_c) {                                           \
      const int _i = i0 + _c, _j = _i >> 3, _rc = _i & 7;                      \
      const u16* _g = W3 + (long)_j * DD                                       \
                    + (long)(bn * 64 + _rc * 8 + (l >> 3)) * K + gcol + _ko;   \
      gload16(_g, _b + 8192 + _j * 4096 + _rc * 512);                          \
    }                                                                          \
  } while (0)

  const int rby  = (l & 15) * 128;
  const int obx0 = ((l >> 4) * 16) ^ ((l & 7) << 4);
  const int lo0  = (rby + obx0) >> 1;      // u16 index
  const int lo1  = lo0 ^ 32;               // ks=1 (byte ^ 64)

  f32x4 acc[3][4] = {};

  auto COMPUTE = [&](int p) {
    const int base = p * 20480;
#pragma unroll
    for (int ks = 0; ks < 2; ++ks) {
      const int lo = ks ? lo1 : lo0;
      bf16x8 af[4], fb[3];
#pragma unroll
      for (int mi = 0; mi < 4; ++mi)
        af[mi] = *reinterpret_cast<const bf16x8*>(
            &lds[base + wm * 4096 + mi * 1024 + lo]);
#pragma unroll
      for (int j = 0; j < 3; ++j)
        fb[j] = *reinterpret_cast<const bf16x8*>(
            &lds[base + 8192 + j * 4096 + wn * 1024 + lo]);
      __builtin_amdgcn_s_setprio(1);
#pragma unroll
      for (int j = 0; j < 3; ++j)
#pragma unroll
        for (int mi = 0; mi < 4; ++mi)
          acc[j][mi] = __builtin_amdgcn_mfma_f32_16x16x32_bf16(
              af[mi], fb[j], acc[j][mi], 0, 0, 0);
      __builtin_amdgcn_s_setprio(0);
    }
  };

  // ---- prologue + R5-proven ping-pong
  STAGE(0);
  VMC(0); BAR;
  for (int t = 0; t < NT - 1; ++t) {
    STAGE(t + 1);
    COMPUTE(t & 1);
    VMC(0); BAR;
  }
  COMPUTE((NT - 1) & 1);
  #undef STAGE

  // ---- fused WKV epilogue (fp32)
  const long row0 = (long)bm * 128 + wm * 64 + (l >> 4) * 4;
  const long gc   = (long)bn * 64 + wn * 16 + (l & 15);
  const float wuv = w_u[gc];
  const float wwv = w_w[gc];
#pragma unroll
  for (int mi = 0; mi < 4; ++mi)
#pragma unroll
    for (int r = 0; r < 4; ++r) {
      const long gr  = row0 + mi * 16 + r;
      const long idx = gr * D_SZ + gc;
      const float rr = acc[0][mi][r];
      const float kk = acc[1][mi][r];
      const float vv = acc[2][mi][r];
      const float n  = frac_n[idx];
      const float dn = frac_d[idx];
      const float s  = scale[idx];

      const float rt  = 1.0f / (1.0f + __expf(-rr));
      const float ss  = fmaxf(s, wuv + kk);
      const float cm  = __expf(s - ss);
      const float am  = __expf(wuv + kk - ss);
      const float fnt = cm * n + am * vv;
      const float fdt = cm * dn + am;

      const float ns2 = fmaxf(s + wwv, kk);
      const float ncm = __expf(s + wwv - ns2);
      const float nam = __expf(kk - ns2);

      o_nfn[idx] = ncm * n + nam * vv;
      o_nfd[idx] = ncm * dn + nam;
      o_ns[idx]  = ns2;
      ab[idx]    = f2bf(rt * (fnt / fdt));
    }
}

// ================================================================ 128x128 bf16 GEMM (out-proj)
// EXACT R9/R5-proven version.
template <bool OUT_BF16>
__global__ __launch_bounds__(256, 4) void k_gemm128(
    const u16* __restrict__ A, const u16* __restrict__ Bm,
    void* __restrict__ C, int M, int N, int K) {
  __shared__ __align__(16) u16 lds[32768];  // 64 KiB
  const int tid = threadIdx.x;
  const int l   = tid & 63;
  const int w   = tid >> 6;
  const int wm  = w >> 1, wn = w & 1;
  const int bm = blockIdx.y, bn = blockIdx.x;
  const int NT = K >> 6;

  const int gcol  = (((l & 7) ^ (l >> 3)) << 3);
  const int grow  = w * 32 + (l >> 3);
  const u16* Abase = A  + (long)(bm * 128 + grow) * K + gcol;
  const u16* Bbase = Bm + (long)(bn * 128 + grow) * K + gcol;
  const int sdst = w * 2048;

  #define STAGE(t) do {                                              \
    const long _ko = (long)(t) * 64;                                 \
    u16* _da = &lds[((t) & 1) * 16384 + sdst];                       \
    u16* _db = _da + 8192;                                           \
    _Pragma("unroll")                                                \
    for (int _c = 0; _c < 4; ++_c) {                                 \
      gload16(Abase + (long)_c * 8 * K + _ko, _da + _c * 512);       \
      gload16(Bbase + (long)_c * 8 * K + _ko, _db + _c * 512);       \
    }                                                                \
  } while (0)

  const int rby  = (l & 15) * 128;
  const int obx0 = ((l >> 4) * 16) ^ ((l & 7) << 4);
  const int lo0  = (rby + obx0) >> 1;
  const int lo1  = lo0 ^ 32;

  f32x4 acc[4][4] = {};

  auto COMPUTE = [&](int p) {
#pragma unroll
    for (int ks = 0; ks < 2; ++ks) {
      const int lo = ks ? lo1 : lo0;
      bf16x8 af[4], bf[4];
#pragma unroll
      for (int mi = 0; mi < 4; ++mi)
        af[mi] = *reinterpret_cast<const bf16x8*>(
            &lds[p * 16384 + (wm * 4 + mi) * 1024 + lo]);
#pragma unroll
      for (int ni = 0; ni < 4; ++ni)
        bf[ni] = *reinterpret_cast<const bf16x8*>(
            &lds[p * 16384 + 8192 + (wn * 4 + ni) * 1024 + lo]);
      __builtin_amdgcn_s_setprio(1);
#pragma unroll
      for (int mi = 0; mi < 4; ++mi)
#pragma unroll
        for (int ni = 0; ni < 4; ++ni)
          acc[mi][ni] = __builtin_amdgcn_mfma_f32_16x16x32_bf16(
              af[mi], bf[ni], acc[mi][ni], 0, 0, 0);
      __builtin_amdgcn_s_setprio(0);
    }
  };

  STAGE(0);
  VMC(0); BAR;
  for (int t = 0; t < NT - 1; ++t) {
    STAGE(t + 1);
    COMPUTE(t & 1);
    VMC(0); BAR;
  }
  COMPUTE((NT - 1) & 1);
  #undef STAGE

  const int rb = (l >> 4) * 4, cb = l & 15;
  const long Crow0 = (long)bm * 128 + wm * 64 + rb;
  const long Ccol0 = (long)bn * 128 + wn * 64 + cb;
#pragma unroll
  for (int mi = 0; mi < 4; ++mi)
#pragma unroll
    for (int ni = 0; ni < 4; ++ni)
#pragma unroll
      for (int r = 0; r < 4; ++r) {
        const long gr = Crow0 + mi * 16 + r;
        const long gc = Ccol0 + ni * 16;
        if constexpr (OUT_BF16)
          ((u16*)C)[gr * N + gc] = f2bf(acc[mi][ni][r]);
        else
          ((float*)C)[gr * N + gc] = acc[mi][ni][r];
      }
}

// ---------------------------------------------------------------- launch
extern "C" void kernel_launch(void* const* d_in, const int* in_sizes, int n_in,
                              void* d_out, int out_size, void* d_ws, size_t ws_size,
                              hipStream_t stream) {
  const float* x      = (const float*)d_in[0];
  const float* frac_n = (const float*)d_in[1];
  const float* frac_d = (const float*)d_in[2];
  const float* scale  = (const float*)d_in[3];
  const float* wr     = (const float*)d_in[4];
  const float* wk     = (const float*)d_in[5];
  const float* wv     = (const float*)d_in[6];
  const float* wo     = (const float*)d_in[7];
  const float* wu     = (const float*)d_in[8];
  const float* ww     = (const float*)d_in[9];
  float* out = (float*)d_out;

  u16* Xb   = (u16*)d_ws;        // BD
  u16* W3b  = Xb + BD;           // 3*DD  (w_r | w_k | w_v rows)
  u16* Wob  = W3b + 3 * DD;      // DD
  u16* ab   = Wob + DD;          // BD

  // 1) fp32 -> bf16 conversions
  {
    const long total = BD + 4 * DD;             // 25165824
    const int blocks = (int)(total / 4 / 256);  // 24576 exact
    k_convert<<<blocks, 256, 0, stream>>>(x, wr, wk, wv, wo, Xb, W3b, Wob);
  }
  // 2) fused rkv GEMM + WKV elementwise: writes next_frac_n/d/scale + a_t(bf16)
  //    grid 32x32 = 1024 blocks = exactly 2 rounds at 2 blocks/CU
  k_fused<<<dim3(D_SZ / 64, B_SZ / 128), 512, 0, stream>>>(
      Xb, W3b, frac_n, frac_d, scale, wu, ww,
      out + BD, out + 2 * BD, out + 3 * BD, ab);
  // 3) output = a @ Wo^T -> d_out[0:BD] fp32
  k_gemm128<false><<<dim3(D_SZ / 128, B_SZ / 128), 256, 0, stream>>>(
      ab, Wob, out, B_SZ, D_SZ, D_SZ);
}